// Round 18
// baseline (183.677 us; speedup 1.0000x reference)
//
#include <hip/hip_runtime.h>
#include <cstdint>
#include <cstddef>

#define NTOK 4096           // B*S
#define DIM  1024           // D
#define HDIM 2048           // H
#define NE   8              // experts
#define BM   128            // GEMM row tile / expert padding
#define MAXROWS (2*NTOK + NE*BM)   // 9216 worst-case padded slots
#define MBLK (MAXROWS/BM)          // 72 m-blocks (fixed grid)

typedef __attribute__((ext_vector_type(8))) short short8;
typedef __attribute__((ext_vector_type(4))) float f32x4;
typedef __attribute__((ext_vector_type(4))) unsigned short u16x4;

__device__ __forceinline__ unsigned short f2bf(float f) {
    union { float f; unsigned int u; } v; v.f = f;
    return (unsigned short)((v.u + 0x7FFFu + ((v.u >> 16) & 1u)) >> 16);
}
__device__ __forceinline__ float bf2f(unsigned short u) {
    union { unsigned int u; float f; } v; v.u = ((unsigned int)u) << 16;
    return v.f;
}

__device__ __forceinline__ void load_lds16(const void* g, void* l) {
    __builtin_amdgcn_global_load_lds(
        (const __attribute__((address_space(1))) void*)(uintptr_t)g,
        (__attribute__((address_space(3))) void*)(uintptr_t)l, 16, 0, 0);
}

// Conflict-free 64x64 f32->bf16 transpose tile (R15-verified): r-pairs packed u32,
// tile [64][37] words; write stride 148w%32=20 (<=2-way free); reads all-16-banks-distinct.
__device__ __forceinline__ void transpose_tile64(
    const float* __restrict__ in, unsigned short* __restrict__ out,
    int R, int C, int bx, int by, int e, unsigned int (*tile2)[37])
{
    in  += (size_t)e * R * C;
    out += (size_t)e * R * C;
    const int c0 = bx * 64, r0 = by * 64;
    const int t = threadIdx.x;
    const int lc = (t & 15) * 4, lrp = t >> 4;   // r-pair 0..15 (+16)
    #pragma unroll
    for (int p = 0; p < 2; ++p) {
        const int rp = lrp + p * 16;
        const int r = rp * 2;
        const float4 v0 = *reinterpret_cast<const float4*>(in + (size_t)(r0 + r)     * C + c0 + lc);
        const float4 v1 = *reinterpret_cast<const float4*>(in + (size_t)(r0 + r + 1) * C + c0 + lc);
        tile2[lc+0][rp] = (unsigned)f2bf(v0.x) | ((unsigned)f2bf(v1.x) << 16);
        tile2[lc+1][rp] = (unsigned)f2bf(v0.y) | ((unsigned)f2bf(v1.y) << 16);
        tile2[lc+2][rp] = (unsigned)f2bf(v0.z) | ((unsigned)f2bf(v1.z) << 16);
        tile2[lc+3][rp] = (unsigned)f2bf(v0.w) | ((unsigned)f2bf(v1.w) << 16);
    }
    __syncthreads();
    const int oc = t >> 2, ok = (t & 3) * 8;     // 8 u32 = 16 consecutive r values
    unsigned int w[8];
    #pragma unroll
    for (int j = 0; j < 8; ++j) w[j] = tile2[oc][ok + j];
    unsigned short* orow = out + (size_t)(c0 + oc) * R + r0 + ok * 2;
    *reinterpret_cast<uint4*>(orow)     = *reinterpret_cast<const uint4*>(&w[0]);
    *reinterpret_cast<uint4*>(orow + 8) = *reinterpret_cast<const uint4*>(&w[4]);
}

// Fused prep: [0,1024) gate (FIRST: overlaps transposes; gw staged stride-1032,
// write bank (8(k&7)+(k>>3))%32 = 2-way free) | [1024,5120) w1T | [5120,9216) w2T | 9216 hdr.
__global__ __launch_bounds__(256) void prep_kernel(
    const float* __restrict__ x,  const float* __restrict__ gw, const float* __restrict__ gb,
    const float* __restrict__ w1, const float* __restrict__ w2,
    unsigned short* __restrict__ w1t, unsigned short* __restrict__ w2t,
    float* __restrict__ scores, int* __restrict__ eidx, float* __restrict__ auxp,
    unsigned short* __restrict__ xbf, int* __restrict__ hdr)
{
    __shared__ float smem[8256];                   // 33 KB: gw^T stride-1032 (gate) / tile2 (transpose)
    const int id = blockIdx.x;
    if (id >= 1024) {
        if (id < 5120) {                           // w1: R=1024, C=2048 -> 32x16 tiles/expert
            const int j = id - 1024;
            const int e = j >> 9, rem = j & 511;
            transpose_tile64(w1, w1t, DIM, HDIM, rem & 31, rem >> 5, e,
                             reinterpret_cast<unsigned int (*)[37]>(smem));
            return;
        }
        if (id < 9216) {                           // w2: R=2048, C=1024 -> 16x32 tiles/expert
            const int j = id - 5120;
            const int e = j >> 9, rem = j & 511;
            transpose_tile64(w2, w2t, HDIM, DIM, rem & 15, rem >> 4, e,
                             reinterpret_cast<unsigned int (*)[37]>(smem));
            return;
        }
        hdr[threadIdx.x] = 0;                      // id == 9216: hdr zero
        return;
    }
    // ---- gate: 4 tokens/block; gw [1024][8] staged transposed into LDS (coalesced, 2-way) ----
    const int tid = threadIdx.x, lane = tid & 63, wv = tid >> 6;
    for (int k = tid; k < 8192; k += 256) {
        const float v = gw[k];                     // fully coalesced fp32
        smem[(k & 7) * 1032 + (k >> 3)] = v;       // LDS-transposed [e][d], stride 1032
    }
    __syncthreads();
    const int n = id * 4 + wv;
    float a[NE] = {0.f,0.f,0.f,0.f,0.f,0.f,0.f,0.f};
    const float* xr = x + (size_t)n * DIM;
    unsigned short* xo = xbf + (size_t)n * DIM;
    #pragma unroll
    for (int c = 0; c < 4; ++c) {
        const int d0 = c * 256 + lane * 4;
        const float4 xv = *reinterpret_cast<const float4*>(xr + d0);
        u16x4 o = { f2bf(xv.x), f2bf(xv.y), f2bf(xv.z), f2bf(xv.w) };
        *reinterpret_cast<u16x4*>(xo + d0) = o;
        #pragma unroll
        for (int e = 0; e < NE; ++e) {
            const float4 gv = *reinterpret_cast<const float4*>(&smem[e * 1032 + d0]);  // aligned, 2-way max
            a[e] = fmaf(xv.x, gv.x, a[e]);
            a[e] = fmaf(xv.y, gv.y, a[e]);
            a[e] = fmaf(xv.z, gv.z, a[e]);
            a[e] = fmaf(xv.w, gv.w, a[e]);
        }
    }
    #pragma unroll
    for (int e = 0; e < NE; ++e)
        #pragma unroll
        for (int off = 32; off > 0; off >>= 1)
            a[e] += __shfl_xor(a[e], off);
    if (lane == 0) {
        float lg[NE], slg = 0.f, mx = -1e30f;
        #pragma unroll
        for (int e = 0; e < NE; ++e) { lg[e] = a[e] + gb[e]; slg += lg[e]; mx = fmaxf(mx, lg[e]); }
        float se = 0.f;
        #pragma unroll
        for (int e = 0; e < NE; ++e) se += expf(lg[e] - mx);
        const float lz = mx + logf(se);
        int i0 = 0;
        #pragma unroll
        for (int e = 1; e < NE; ++e) if (lg[e] > lg[i0]) i0 = e;
        int i1 = (i0 == 0) ? 1 : 0;
        #pragma unroll
        for (int e = 0; e < NE; ++e) if (e != i0 && lg[e] > lg[i1]) i1 = e;
        const float ex = expf(lg[i1] - lg[i0]);
        const float p0 = 1.f / (1.f + ex);
        scores[2*n]   = p0;
        scores[2*n+1] = ex * p0;
        eidx[2*n]   = i0;
        eidx[2*n+1] = i1;
        auxp[n] = slg - 8.f * lz;           // sum_e logp_e for this token (no atomics)
    }
}

// Fused hist+assign: each of 32 blocks re-histograms ALL eidx (L2-hot, ~32KB),
// computes 128-padded offsets locally (writes identical hdr[16..24] - benign race),
// then assigns its 256 pairs via spread global cursors.
__global__ __launch_bounds__(256) void assign_kernel(
    const int* __restrict__ eidx, int* __restrict__ hdr, int* __restrict__ slot_of,
    int* __restrict__ s2t)
{
    __shared__ int cnt[NE];
    __shared__ int cnt2[NE];
    __shared__ int base[NE];
    __shared__ int offs[NE + 1];
    const int tid = threadIdx.x, lane = tid & 63;
    if (tid < NE) { cnt[tid] = 0; cnt2[tid] = 0; }
    __syncthreads();
    int local[NE] = {0,0,0,0,0,0,0,0};
    #pragma unroll
    for (int j = 0; j < 32; ++j) {
        const int e = eidx[j * 256 + tid];
        #pragma unroll
        for (int k = 0; k < NE; ++k) local[k] += (e == k);
    }
    #pragma unroll
    for (int k = 0; k < NE; ++k)
        #pragma unroll
        for (int off = 32; off > 0; off >>= 1)
            local[k] += __shfl_xor(local[k], off);
    if (lane == 0)
        #pragma unroll
        for (int k = 0; k < NE; ++k) atomicAdd(&cnt[k], local[k]);   // LDS atomics
    __syncthreads();
    if (tid == 0) {
        int off = 0;
        #pragma unroll
        for (int e = 0; e < NE; ++e) {
            offs[e] = off;
            hdr[16 + e] = off;                     // all blocks write identical values
            off += (cnt[e] + BM - 1) & ~(BM - 1);
        }
        offs[NE] = off;
        hdr[16 + NE] = off;                        // padded_total
    }
    __syncthreads();
    const int p = blockIdx.x * 256 + tid;
    const int e = eidx[p];
    const int pos = atomicAdd(&cnt2[e], 1);        // LDS atomic
    __syncthreads();
    if (tid < NE) base[tid] = atomicAdd(&hdr[32 + 16 * tid], cnt2[tid]);  // own cacheline
    __syncthreads();
    const int slot = offs[e] + base[e] + pos;
    slot_of[p] = slot;
    s2t[slot] = p >> 1;                            // token of this slot (pad slots: stale, clamped in gemm)
}

// C[row][n] = (GELU? gelu : id)(A[row][:] @ B_e[:][n]);  A:[*][KD] bf16, Bt:[E][ND][KD] bf16
// R6/R12-proven: 128x128 tile, 4 waves, BK=32, 3-deep LDS pipeline (48 KB),
// counted vmcnt(8/4/0), XOR bank swizzle (measured zero-conflict), slot->token gather on A.
template<int KD, int ND, bool GELU, bool GATHER>
__global__ __launch_bounds__(256, 2) void gemm_kernel(
    const unsigned short* __restrict__ A, const unsigned short* __restrict__ Bt,
    unsigned short* __restrict__ Cout, const int* __restrict__ hdr, const int* __restrict__ s2t)
{
    const int tid = threadIdx.x, lane = tid & 63, wv = tid >> 6;
    const int wr = wv >> 1, wc = wv & 1;
    const int row0 = blockIdx.y * BM;
    if (row0 >= hdr[16 + NE]) return;          // beyond padded_total (uniform)
    int e = 0;
    while (e < NE - 1 && hdr[16 + e + 1] <= row0) ++e;
    const unsigned short* Be = Bt + (size_t)e * KD * ND + (size_t)(blockIdx.x * 128) * KD;

    // 3 buffers x (A 4096 shorts | B 4096 shorts) = 48 KB
    __shared__ __align__(16) unsigned short lds[3 * 8192];

    f32x4 acc[4][4] = {};
    const int srow = lane >> 2;
    const int scolX = (((lane & 3) ^ ((lane >> 3) & 3)) * 8);   // swizzled source col (elements)
    const int ch0 = wv * 2, ch1 = ch0 + 1;                      // wave-uniform chunk ids

    // per-thread global A rows (resolved once; GATHER indirects slot->token, clamped)
    int ta0 = row0 + ch0 * 16 + srow, ta1 = row0 + ch1 * 16 + srow;
    if (GATHER) {
        int t0 = s2t[ta0]; if ((unsigned)t0 >= NTOK) t0 = 0; ta0 = t0;   // pad slots: any valid row
        int t1 = s2t[ta1]; if ((unsigned)t1 >= NTOK) t1 = 0; ta1 = t1;
    }
    const size_t ga0 = (size_t)ta0 * KD, ga1 = (size_t)ta1 * KD;
    const size_t gb0 = (size_t)(ch0 * 16 + srow) * KD;
    const size_t gb1 = (size_t)(ch1 * 16 + srow) * KD;

    auto STAGE = [&](unsigned off, int k0) {   // off in shorts
        load_lds16(A  + ga0 + k0 + scolX, &lds[off + ch0 * 512]);
        load_lds16(A  + ga1 + k0 + scolX, &lds[off + ch1 * 512]);
        load_lds16(Be + gb0 + k0 + scolX, &lds[off + 4096 + ch0 * 512]);
        load_lds16(Be + gb1 + k0 + scolX, &lds[off + 4096 + ch1 * 512]);
    };

    const int r = lane & 15;
    const int hsegX = (((lane >> 4) ^ ((r >> 1) & 3)) * 8);     // swizzled frag col (shorts)

    unsigned o0 = 0, o1 = 8192, o2 = 16384;
    STAGE(o0, 0);
    STAGE(o1, 32);
    const int NT = KD / 32;
    for (int t = 0; t < NT; ++t) {
        if (t + 2 < NT) {
            STAGE(o2, (t + 2) * 32);                              // prefetch 2 ahead
            asm volatile("s_waitcnt vmcnt(8)" ::: "memory");      // tile t landed
        } else if (t + 1 < NT) {
            asm volatile("s_waitcnt vmcnt(4)" ::: "memory");
        } else {
            asm volatile("s_waitcnt vmcnt(0)" ::: "memory");
        }
        __builtin_amdgcn_s_barrier();          // all waves' tile-t loads landed
        __builtin_amdgcn_sched_barrier(0);
        short8 af[4], bfr[4];
        #pragma unroll
        for (int mm = 0; mm < 4; ++mm)
            af[mm] = *reinterpret_cast<const short8*>(&lds[o0 + (wr*64 + mm*16 + r) * 32 + hsegX]);
        #pragma unroll
        for (int nn = 0; nn < 4; ++nn)
            bfr[nn] = *reinterpret_cast<const short8*>(&lds[o0 + 4096 + (wc*64 + nn*16 + r) * 32 + hsegX]);
        __builtin_amdgcn_s_setprio(1);
        #pragma unroll
        for (int mm = 0; mm < 4; ++mm)
            #pragma unroll
            for (int nn = 0; nn < 4; ++nn)
                acc[mm][nn] = __builtin_amdgcn_mfma_f32_16x16x32_bf16(af[mm], bfr[nn], acc[mm][nn], 0, 0, 0);
        __builtin_amdgcn_s_setprio(0);
        __builtin_amdgcn_sched_barrier(0);
        __builtin_amdgcn_s_barrier();          // reads of o0 done -> next STAGE may overwrite
        const unsigned tmp = o0; o0 = o1; o1 = o2; o2 = tmp;
    }

    const int col = lane & 15, rb = (lane >> 4) * 4;      // C/D: col=lane&15, row=(lane>>4)*4+j
    #pragma unroll
    for (int mm = 0; mm < 4; ++mm)
        #pragma unroll
        for (int nn = 0; nn < 4; ++nn)
            #pragma unroll
            for (int j = 0; j < 4; ++j) {
                const int grow = row0 + wr*64 + mm*16 + rb + j;
                const int gcol = blockIdx.x * 128 + wc*64 + nn*16 + col;
                float v = acc[mm][nn][j];
                if (GELU) v = 0.5f * v * (1.0f + erff(v * 0.70710678118654752f));
                Cout[(size_t)grow * ND + gcol] = f2bf(v);
            }
}

// combine (blocks 0..NTOK-1) + aux reduction (block NTOK)
__global__ __launch_bounds__(256) void combine_aux_kernel(
    const unsigned short* __restrict__ sout, const float* __restrict__ scores,
    const int* __restrict__ slot_of, const float* __restrict__ auxp, float* __restrict__ out)
{
    const int n = blockIdx.x;
    const int tid = threadIdx.x;
    if (n == NTOK) {                           // aux loss
        __shared__ float red[4];
        const int lane = tid & 63, wv = tid >> 6;
        float s = 0.f;
        for (int i = tid; i < NTOK; i += 256) s += auxp[i];
        #pragma unroll
        for (int off = 32; off > 0; off >>= 1) s += __shfl_xor(s, off);
        if (lane == 0) red[wv] = s;
        __syncthreads();
        if (tid == 0) {
            const float tot = red[0] + red[1] + red[2] + red[3];
            const float t = 0.125f;
            out[(size_t)NTOK * DIM] = 0.01f * t * (logf(t) - tot / (float)(NTOK * NE));
        }
        return;
    }
    const float s0 = scores[2*n], s1 = scores[2*n+1];
    const int sa = slot_of[2*n], sb = slot_of[2*n+1];
    const int d = tid * 4;
    const u16x4 va = *reinterpret_cast<const u16x4*>(sout + (size_t)sa * DIM + d);
    const u16x4 vb = *reinterpret_cast<const u16x4*>(sout + (size_t)sb * DIM + d);
    float4 o;
    o.x = s0*bf2f(va.x) + s1*bf2f(vb.x);
    o.y = s0*bf2f(va.y) + s1*bf2f(vb.y);
    o.z = s0*bf2f(va.z) + s1*bf2f(vb.z);
    o.w = s0*bf2f(va.w) + s1*bf2f(vb.w);
    *reinterpret_cast<float4*>(out + (size_t)n * DIM + d) = o;
}

// ---- workspace layout (bytes) ----
constexpr size_t OFF_SCORES = 2048;
constexpr size_t OFF_IDX    = OFF_SCORES + (size_t)NTOK * 2 * 4;
constexpr size_t OFF_SLOT   = OFF_IDX    + (size_t)NTOK * 2 * 4;
constexpr size_t OFF_AUXP   = OFF_SLOT   + (size_t)NTOK * 2 * 4;
constexpr size_t OFF_S2T    = OFF_AUXP   + (size_t)NTOK * 4;
constexpr size_t OFF_XBF    = 262144;
constexpr size_t OFF_W1T    = OFF_XBF + (size_t)NTOK * DIM * 2;
constexpr size_t OFF_W2T    = OFF_W1T + (size_t)NE * DIM * HDIM * 2;
constexpr size_t OFF_H      = OFF_W2T + (size_t)NE * DIM * HDIM * 2;
constexpr size_t OFF_SOUT   = OFF_H   + (size_t)MAXROWS * HDIM * 2;
constexpr size_t WS_NEED    = OFF_SOUT + (size_t)MAXROWS * DIM * 2;

extern "C" void kernel_launch(void* const* d_in, const int* in_sizes, int n_in,
                              void* d_out, int out_size, void* d_ws, size_t ws_size,
                              hipStream_t stream) {
    const float* x  = (const float*)d_in[0];
    const float* gw = (const float*)d_in[1];
    const float* gb = (const float*)d_in[2];
    const float* w1 = (const float*)d_in[3];
    const float* w2 = (const float*)d_in[4];
    float* out = (float*)d_out;

    if (ws_size < WS_NEED) return;   // fail loudly (output stays poisoned)

    char* ws = (char*)d_ws;
    int*   hdr     = (int*)ws;
    float* scores  = (float*)(ws + OFF_SCORES);
    int*   eidx    = (int*)(ws + OFF_IDX);
    int*   slot_of = (int*)(ws + OFF_SLOT);
    float* auxp    = (float*)(ws + OFF_AUXP);
    int*   s2t     = (int*)(ws + OFF_S2T);
    unsigned short* xbf = (unsigned short*)(ws + OFF_XBF);
    unsigned short* w1t = (unsigned short*)(ws + OFF_W1T);
    unsigned short* w2t = (unsigned short*)(ws + OFF_W2T);
    unsigned short* h   = (unsigned short*)(ws + OFF_H);
    unsigned short* sout= (unsigned short*)(ws + OFF_SOUT);

    prep_kernel<<<9217, 256, 0, stream>>>(x, gw, gb, w1, w2, w1t, w2t,
                                          scores, eidx, auxp, xbf, hdr);
    assign_kernel<<<2*NTOK/256, 256, 0, stream>>>(eidx, hdr, slot_of, s2t);
    gemm_kernel<DIM, HDIM, true,  true ><<<dim3(HDIM/128, MBLK), 256, 0, stream>>>(xbf, w1t, h, hdr, s2t);
    gemm_kernel<HDIM, DIM, false, false><<<dim3(DIM/128, MBLK), 256, 0, stream>>>(h, w2t, sout, hdr, s2t);
    combine_aux_kernel<<<NTOK + 1, 256, 0, stream>>>(sout, scores, slot_of, auxp, out);
}

// Round 19
// 182.959 us; speedup vs baseline: 1.0039x; 1.0039x over previous
//
#include <hip/hip_runtime.h>
#include <cstdint>
#include <cstddef>

#define NTOK 4096           // B*S
#define DIM  1024           // D
#define HDIM 2048           // H
#define NE   8              // experts
#define BM   128            // GEMM row tile / expert padding
#define MAXROWS (2*NTOK + NE*BM)   // 9216 worst-case padded slots
#define MBLK (MAXROWS/BM)          // 72 m-blocks (fixed grid)

typedef __attribute__((ext_vector_type(8))) short short8;
typedef __attribute__((ext_vector_type(4))) float f32x4;
typedef __attribute__((ext_vector_type(4))) unsigned short u16x4;

__device__ __forceinline__ unsigned short f2bf(float f) {
    union { float f; unsigned int u; } v; v.f = f;
    return (unsigned short)((v.u + 0x7FFFu + ((v.u >> 16) & 1u)) >> 16);
}
__device__ __forceinline__ float bf2f(unsigned short u) {
    union { unsigned int u; float f; } v; v.u = ((unsigned int)u) << 16;
    return v.f;
}
__device__ __forceinline__ unsigned int pack2(float lo, float hi) {
    return (unsigned)f2bf(lo) | ((unsigned)f2bf(hi) << 16);
}

__device__ __forceinline__ void load_lds16(const void* g, void* l) {
    __builtin_amdgcn_global_load_lds(
        (const __attribute__((address_space(1))) void*)(uintptr_t)g,
        (__attribute__((address_space(3))) void*)(uintptr_t)l, 16, 0, 0);
}

// Paired conflict-free 64x64 f32->bf16 transpose: 2 tiles/block, all 4 float4 loads
// in flight before LDS writes, one sync. tile2 [128][37] u32 (R15-verified bank map;
// +64-row offset = 2368w = 0 mod 32 banks, same pattern).
__device__ __forceinline__ void transpose_pair(
    const float* __restrict__ in, unsigned short* __restrict__ out,
    int R, int C, int e, int bx0, int by0, int bx1, int by1,
    unsigned int (*tile2)[37])
{
    const float* base = in + (size_t)e * R * C;
    unsigned short* obase = out + (size_t)e * R * C;
    const int t = threadIdx.x;
    const int lc = (t & 15) * 4, lrp = t >> 4;   // r-pair 0..15 (+16)
    float4 va[2][2], vb[2][2];                   // [tile][p]
    #pragma unroll
    for (int p = 0; p < 2; ++p) {
        const int r = (lrp + p * 16) * 2;
        va[0][p] = *reinterpret_cast<const float4*>(base + (size_t)(by0*64 + r)     * C + bx0*64 + lc);
        vb[0][p] = *reinterpret_cast<const float4*>(base + (size_t)(by0*64 + r + 1) * C + bx0*64 + lc);
        va[1][p] = *reinterpret_cast<const float4*>(base + (size_t)(by1*64 + r)     * C + bx1*64 + lc);
        vb[1][p] = *reinterpret_cast<const float4*>(base + (size_t)(by1*64 + r + 1) * C + bx1*64 + lc);
    }
    #pragma unroll
    for (int tt = 0; tt < 2; ++tt)
        #pragma unroll
        for (int p = 0; p < 2; ++p) {
            const int rp = lrp + p * 16;
            tile2[tt*64 + lc+0][rp] = pack2(va[tt][p].x, vb[tt][p].x);
            tile2[tt*64 + lc+1][rp] = pack2(va[tt][p].y, vb[tt][p].y);
            tile2[tt*64 + lc+2][rp] = pack2(va[tt][p].z, vb[tt][p].z);
            tile2[tt*64 + lc+3][rp] = pack2(va[tt][p].w, vb[tt][p].w);
        }
    __syncthreads();
    const int oc = t >> 2, ok = (t & 3) * 8;     // 8 u32 = 16 consecutive r values
    #pragma unroll
    for (int tt = 0; tt < 2; ++tt) {
        unsigned int w[8];
        #pragma unroll
        for (int j = 0; j < 8; ++j) w[j] = tile2[tt*64 + oc][ok + j];
        const int bx = tt ? bx1 : bx0, by = tt ? by1 : by0;
        unsigned short* orow = obase + (size_t)(bx*64 + oc) * R + by*64 + ok * 2;
        *reinterpret_cast<uint4*>(orow)     = *reinterpret_cast<const uint4*>(&w[0]);
        *reinterpret_cast<uint4*>(orow + 8) = *reinterpret_cast<const uint4*>(&w[4]);
    }
}

// Fused prep: [0,1024) gate (gw staged float4->LDS-transposed stride-1032, 2-way free)
// | [1024,3072) w1T pairs | [3072,5120) w2T pairs | 5120 hdr zero.
__global__ __launch_bounds__(256) void prep_kernel(
    const float* __restrict__ x,  const float* __restrict__ gw, const float* __restrict__ gb,
    const float* __restrict__ w1, const float* __restrict__ w2,
    unsigned short* __restrict__ w1t, unsigned short* __restrict__ w2t,
    float* __restrict__ scores, int* __restrict__ eidx, float* __restrict__ auxp,
    unsigned short* __restrict__ xbf, int* __restrict__ hdr)
{
    __shared__ float smem[8256];                   // 33 KB: gw^T (gate) / tile2 [128][37] (transpose)
    const int id = blockIdx.x;
    if (id >= 1024) {
        if (id < 3072) {                           // w1 pairs: R=1024, C=2048, 32x16 tiles/expert
            const int p = id - 1024;               // pair index
            const int j0 = 2 * p;
            const int e = j0 >> 9, rem = j0 & 511; // rem even -> rem+1 same e
            transpose_pair(w1, w1t, DIM, HDIM, e, rem & 31, rem >> 5,
                           (rem + 1) & 31, (rem + 1) >> 5,
                           reinterpret_cast<unsigned int (*)[37]>(smem));
            return;
        }
        if (id < 5120) {                           // w2 pairs: R=2048, C=1024, 16x32 tiles/expert
            const int p = id - 3072;
            const int j0 = 2 * p;
            const int e = j0 >> 9, rem = j0 & 511;
            transpose_pair(w2, w2t, HDIM, DIM, e, rem & 15, rem >> 4,
                           (rem + 1) & 15, (rem + 1) >> 4,
                           reinterpret_cast<unsigned int (*)[37]>(smem));
            return;
        }
        hdr[threadIdx.x] = 0;                      // id == 5120: hdr zero
        return;
    }
    // ---- gate: 4 tokens/block; gw [1024][8] staged float4 -> LDS-transposed (2-way max) ----
    const int tid = threadIdx.x, lane = tid & 63, wv = tid >> 6;
    for (int k4 = tid * 4; k4 < 8192; k4 += 1024) {
        const float4 v = *reinterpret_cast<const float4*>(gw + k4);   // 16B/lane coalesced
        const int d = k4 >> 3, eb = k4 & 7;        // eb in {0,4}
        smem[(eb + 0) * 1032 + d] = v.x;
        smem[(eb + 1) * 1032 + d] = v.y;
        smem[(eb + 2) * 1032 + d] = v.z;
        smem[(eb + 3) * 1032 + d] = v.w;
    }
    __syncthreads();
    const int n = id * 4 + wv;
    float a[NE] = {0.f,0.f,0.f,0.f,0.f,0.f,0.f,0.f};
    const float* xr = x + (size_t)n * DIM;
    unsigned short* xo = xbf + (size_t)n * DIM;
    #pragma unroll
    for (int c = 0; c < 4; ++c) {
        const int d0 = c * 256 + lane * 4;
        const float4 xv = *reinterpret_cast<const float4*>(xr + d0);
        u16x4 o = { f2bf(xv.x), f2bf(xv.y), f2bf(xv.z), f2bf(xv.w) };
        *reinterpret_cast<u16x4*>(xo + d0) = o;
        #pragma unroll
        for (int e = 0; e < NE; ++e) {
            const float4 gv = *reinterpret_cast<const float4*>(&smem[e * 1032 + d0]);  // aligned, 2-way max
            a[e] = fmaf(xv.x, gv.x, a[e]);
            a[e] = fmaf(xv.y, gv.y, a[e]);
            a[e] = fmaf(xv.z, gv.z, a[e]);
            a[e] = fmaf(xv.w, gv.w, a[e]);
        }
    }
    #pragma unroll
    for (int e = 0; e < NE; ++e)
        #pragma unroll
        for (int off = 32; off > 0; off >>= 1)
            a[e] += __shfl_xor(a[e], off);
    if (lane == 0) {
        float lg[NE], slg = 0.f, mx = -1e30f;
        #pragma unroll
        for (int e = 0; e < NE; ++e) { lg[e] = a[e] + gb[e]; slg += lg[e]; mx = fmaxf(mx, lg[e]); }
        float se = 0.f;
        #pragma unroll
        for (int e = 0; e < NE; ++e) se += expf(lg[e] - mx);
        const float lz = mx + logf(se);
        int i0 = 0;
        #pragma unroll
        for (int e = 1; e < NE; ++e) if (lg[e] > lg[i0]) i0 = e;
        int i1 = (i0 == 0) ? 1 : 0;
        #pragma unroll
        for (int e = 0; e < NE; ++e) if (e != i0 && lg[e] > lg[i1]) i1 = e;
        const float ex = expf(lg[i1] - lg[i0]);
        const float p0 = 1.f / (1.f + ex);
        scores[2*n]   = p0;
        scores[2*n+1] = ex * p0;
        eidx[2*n]   = i0;
        eidx[2*n+1] = i1;
        auxp[n] = slg - 8.f * lz;           // sum_e logp_e for this token (no atomics)
    }
}

// Fused hist+assign: each of 32 blocks re-histograms ALL eidx (L2-hot, ~32KB),
// computes 128-padded offsets locally (writes identical hdr[16..24] - benign race),
// then assigns its 256 pairs via spread global cursors.
__global__ __launch_bounds__(256) void assign_kernel(
    const int* __restrict__ eidx, int* __restrict__ hdr, int* __restrict__ slot_of,
    int* __restrict__ s2t)
{
    __shared__ int cnt[NE];
    __shared__ int cnt2[NE];
    __shared__ int base[NE];
    __shared__ int offs[NE + 1];
    const int tid = threadIdx.x, lane = tid & 63;
    if (tid < NE) { cnt[tid] = 0; cnt2[tid] = 0; }
    __syncthreads();
    int local[NE] = {0,0,0,0,0,0,0,0};
    #pragma unroll
    for (int j = 0; j < 32; ++j) {
        const int e = eidx[j * 256 + tid];
        #pragma unroll
        for (int k = 0; k < NE; ++k) local[k] += (e == k);
    }
    #pragma unroll
    for (int k = 0; k < NE; ++k)
        #pragma unroll
        for (int off = 32; off > 0; off >>= 1)
            local[k] += __shfl_xor(local[k], off);
    if (lane == 0)
        #pragma unroll
        for (int k = 0; k < NE; ++k) atomicAdd(&cnt[k], local[k]);   // LDS atomics
    __syncthreads();
    if (tid == 0) {
        int off = 0;
        #pragma unroll
        for (int e = 0; e < NE; ++e) {
            offs[e] = off;
            hdr[16 + e] = off;                     // all blocks write identical values
            off += (cnt[e] + BM - 1) & ~(BM - 1);
        }
        offs[NE] = off;
        hdr[16 + NE] = off;                        // padded_total
    }
    __syncthreads();
    const int p = blockIdx.x * 256 + tid;
    const int e = eidx[p];
    const int pos = atomicAdd(&cnt2[e], 1);        // LDS atomic
    __syncthreads();
    if (tid < NE) base[tid] = atomicAdd(&hdr[32 + 16 * tid], cnt2[tid]);  // own cacheline
    __syncthreads();
    const int slot = offs[e] + base[e] + pos;
    slot_of[p] = slot;
    s2t[slot] = p >> 1;                            // token of this slot (pad slots: stale, clamped in gemm)
}

// C[row][n] = (GELU? gelu : id)(A[row][:] @ B_e[:][n]);  A:[*][KD] bf16, Bt:[E][ND][KD] bf16
// R6/R12-proven: 128x128 tile, 4 waves, BK=32, 3-deep LDS pipeline (48 KB),
// counted vmcnt(8/4/0), XOR bank swizzle (measured zero-conflict), slot->token gather on A.
template<int KD, int ND, bool GELU, bool GATHER>
__global__ __launch_bounds__(256, 2) void gemm_kernel(
    const unsigned short* __restrict__ A, const unsigned short* __restrict__ Bt,
    unsigned short* __restrict__ Cout, const int* __restrict__ hdr, const int* __restrict__ s2t)
{
    const int tid = threadIdx.x, lane = tid & 63, wv = tid >> 6;
    const int wr = wv >> 1, wc = wv & 1;
    const int row0 = blockIdx.y * BM;
    if (row0 >= hdr[16 + NE]) return;          // beyond padded_total (uniform)
    int e = 0;
    while (e < NE - 1 && hdr[16 + e + 1] <= row0) ++e;
    const unsigned short* Be = Bt + (size_t)e * KD * ND + (size_t)(blockIdx.x * 128) * KD;

    // 3 buffers x (A 4096 shorts | B 4096 shorts) = 48 KB
    __shared__ __align__(16) unsigned short lds[3 * 8192];

    f32x4 acc[4][4] = {};
    const int srow = lane >> 2;
    const int scolX = (((lane & 3) ^ ((lane >> 3) & 3)) * 8);   // swizzled source col (elements)
    const int ch0 = wv * 2, ch1 = ch0 + 1;                      // wave-uniform chunk ids

    // per-thread global A rows (resolved once; GATHER indirects slot->token, clamped)
    int ta0 = row0 + ch0 * 16 + srow, ta1 = row0 + ch1 * 16 + srow;
    if (GATHER) {
        int t0 = s2t[ta0]; if ((unsigned)t0 >= NTOK) t0 = 0; ta0 = t0;   // pad slots: any valid row
        int t1 = s2t[ta1]; if ((unsigned)t1 >= NTOK) t1 = 0; ta1 = t1;
    }
    const size_t ga0 = (size_t)ta0 * KD, ga1 = (size_t)ta1 * KD;
    const size_t gb0 = (size_t)(ch0 * 16 + srow) * KD;
    const size_t gb1 = (size_t)(ch1 * 16 + srow) * KD;

    auto STAGE = [&](unsigned off, int k0) {   // off in shorts
        load_lds16(A  + ga0 + k0 + scolX, &lds[off + ch0 * 512]);
        load_lds16(A  + ga1 + k0 + scolX, &lds[off + ch1 * 512]);
        load_lds16(Be + gb0 + k0 + scolX, &lds[off + 4096 + ch0 * 512]);
        load_lds16(Be + gb1 + k0 + scolX, &lds[off + 4096 + ch1 * 512]);
    };

    const int r = lane & 15;
    const int hsegX = (((lane >> 4) ^ ((r >> 1) & 3)) * 8);     // swizzled frag col (shorts)

    unsigned o0 = 0, o1 = 8192, o2 = 16384;
    STAGE(o0, 0);
    STAGE(o1, 32);
    const int NT = KD / 32;
    for (int t = 0; t < NT; ++t) {
        if (t + 2 < NT) {
            STAGE(o2, (t + 2) * 32);                              // prefetch 2 ahead
            asm volatile("s_waitcnt vmcnt(8)" ::: "memory");      // tile t landed
        } else if (t + 1 < NT) {
            asm volatile("s_waitcnt vmcnt(4)" ::: "memory");
        } else {
            asm volatile("s_waitcnt vmcnt(0)" ::: "memory");
        }
        __builtin_amdgcn_s_barrier();          // all waves' tile-t loads landed
        __builtin_amdgcn_sched_barrier(0);
        short8 af[4], bfr[4];
        #pragma unroll
        for (int mm = 0; mm < 4; ++mm)
            af[mm] = *reinterpret_cast<const short8*>(&lds[o0 + (wr*64 + mm*16 + r) * 32 + hsegX]);
        #pragma unroll
        for (int nn = 0; nn < 4; ++nn)
            bfr[nn] = *reinterpret_cast<const short8*>(&lds[o0 + 4096 + (wc*64 + nn*16 + r) * 32 + hsegX]);
        __builtin_amdgcn_s_setprio(1);
        #pragma unroll
        for (int mm = 0; mm < 4; ++mm)
            #pragma unroll
            for (int nn = 0; nn < 4; ++nn)
                acc[mm][nn] = __builtin_amdgcn_mfma_f32_16x16x32_bf16(af[mm], bfr[nn], acc[mm][nn], 0, 0, 0);
        __builtin_amdgcn_s_setprio(0);
        __builtin_amdgcn_sched_barrier(0);
        __builtin_amdgcn_s_barrier();          // reads of o0 done -> next STAGE may overwrite
        const unsigned tmp = o0; o0 = o1; o1 = o2; o2 = tmp;
    }

    const int col = lane & 15, rb = (lane >> 4) * 4;      // C/D: col=lane&15, row=(lane>>4)*4+j
    #pragma unroll
    for (int mm = 0; mm < 4; ++mm)
        #pragma unroll
        for (int nn = 0; nn < 4; ++nn)
            #pragma unroll
            for (int j = 0; j < 4; ++j) {
                const int grow = row0 + wr*64 + mm*16 + rb + j;
                const int gcol = blockIdx.x * 128 + wc*64 + nn*16 + col;
                float v = acc[mm][nn][j];
                if (GELU) v = 0.5f * v * (1.0f + erff(v * 0.70710678118654752f));
                Cout[(size_t)grow * ND + gcol] = f2bf(v);
            }
}

// combine (blocks 0..NTOK-1) + aux reduction (block NTOK)
__global__ __launch_bounds__(256) void combine_aux_kernel(
    const unsigned short* __restrict__ sout, const float* __restrict__ scores,
    const int* __restrict__ slot_of, const float* __restrict__ auxp, float* __restrict__ out)
{
    const int n = blockIdx.x;
    const int tid = threadIdx.x;
    if (n == NTOK) {                           // aux loss
        __shared__ float red[4];
        const int lane = tid & 63, wv = tid >> 6;
        float s = 0.f;
        for (int i = tid; i < NTOK; i += 256) s += auxp[i];
        #pragma unroll
        for (int off = 32; off > 0; off >>= 1) s += __shfl_xor(s, off);
        if (lane == 0) red[wv] = s;
        __syncthreads();
        if (tid == 0) {
            const float tot = red[0] + red[1] + red[2] + red[3];
            const float t = 0.125f;
            out[(size_t)NTOK * DIM] = 0.01f * t * (logf(t) - tot / (float)(NTOK * NE));
        }
        return;
    }
    const float s0 = scores[2*n], s1 = scores[2*n+1];
    const int sa = slot_of[2*n], sb = slot_of[2*n+1];
    const int d = tid * 4;
    const u16x4 va = *reinterpret_cast<const u16x4*>(sout + (size_t)sa * DIM + d);
    const u16x4 vb = *reinterpret_cast<const u16x4*>(sout + (size_t)sb * DIM + d);
    float4 o;
    o.x = s0*bf2f(va.x) + s1*bf2f(vb.x);
    o.y = s0*bf2f(va.y) + s1*bf2f(vb.y);
    o.z = s0*bf2f(va.z) + s1*bf2f(vb.z);
    o.w = s0*bf2f(va.w) + s1*bf2f(vb.w);
    *reinterpret_cast<float4*>(out + (size_t)n * DIM + d) = o;
}

// ---- workspace layout (bytes) ----
constexpr size_t OFF_SCORES = 2048;
constexpr size_t OFF_IDX    = OFF_SCORES + (size_t)NTOK * 2 * 4;
constexpr size_t OFF_SLOT   = OFF_IDX    + (size_t)NTOK * 2 * 4;
constexpr size_t OFF_AUXP   = OFF_SLOT   + (size_t)NTOK * 2 * 4;
constexpr size_t OFF_S2T    = OFF_AUXP   + (size_t)NTOK * 4;
constexpr size_t OFF_XBF    = 262144;
constexpr size_t OFF_W1T    = OFF_XBF + (size_t)NTOK * DIM * 2;
constexpr size_t OFF_W2T    = OFF_W1T + (size_t)NE * DIM * HDIM * 2;
constexpr size_t OFF_H      = OFF_W2T + (size_t)NE * DIM * HDIM * 2;
constexpr size_t OFF_SOUT   = OFF_H   + (size_t)MAXROWS * HDIM * 2;
constexpr size_t WS_NEED    = OFF_SOUT + (size_t)MAXROWS * DIM * 2;

extern "C" void kernel_launch(void* const* d_in, const int* in_sizes, int n_in,
                              void* d_out, int out_size, void* d_ws, size_t ws_size,
                              hipStream_t stream) {
    const float* x  = (const float*)d_in[0];
    const float* gw = (const float*)d_in[1];
    const float* gb = (const float*)d_in[2];
    const float* w1 = (const float*)d_in[3];
    const float* w2 = (const float*)d_in[4];
    float* out = (float*)d_out;

    if (ws_size < WS_NEED) return;   // fail loudly (output stays poisoned)

    char* ws = (char*)d_ws;
    int*   hdr     = (int*)ws;
    float* scores  = (float*)(ws + OFF_SCORES);
    int*   eidx    = (int*)(ws + OFF_IDX);
    int*   slot_of = (int*)(ws + OFF_SLOT);
    float* auxp    = (float*)(ws + OFF_AUXP);
    int*   s2t     = (int*)(ws + OFF_S2T);
    unsigned short* xbf = (unsigned short*)(ws + OFF_XBF);
    unsigned short* w1t = (unsigned short*)(ws + OFF_W1T);
    unsigned short* w2t = (unsigned short*)(ws + OFF_W2T);
    unsigned short* h   = (unsigned short*)(ws + OFF_H);
    unsigned short* sout= (unsigned short*)(ws + OFF_SOUT);

    prep_kernel<<<5121, 256, 0, stream>>>(x, gw, gb, w1, w2, w1t, w2t,
                                          scores, eidx, auxp, xbf, hdr);
    assign_kernel<<<2*NTOK/256, 256, 0, stream>>>(eidx, hdr, slot_of, s2t);
    gemm_kernel<DIM, HDIM, true,  true ><<<dim3(HDIM/128, MBLK), 256, 0, stream>>>(xbf, w1t, h, hdr, s2t);
    gemm_kernel<HDIM, DIM, false, false><<<dim3(DIM/128, MBLK), 256, 0, stream>>>(h, w2t, sout, hdr, s2t);
    combine_aux_kernel<<<NTOK + 1, 256, 0, stream>>>(sout, scores, slot_of, auxp, out);
}